// Round 1
// baseline (179617.859 us; speedup 1.0000x reference)
//
#include <hip/hip_runtime.h>

#define LOG2E   1.4426950408889634f
#define CAP     14      // max fan-in slots per lane (after load balancing)
#define LEVELS  17
#define UNITS   51
#define VAR_N   4
#define PRED_N  28
#define UNFOLDS 6

// ---------------------------------------------------------------------------
// Prep: build sparse fan-in slot tables from mask (data-driven, runs per call).
// Lane assignment: primary lane u (u<51) owns output unit u; spare lanes 51..63
// are greedily given to the outputs with the largest per-lane fan-in share.
// Per (var,lane,slot): {src_unit, c1=-log2e*sigma, c2=log2e*sigma*mu, wn=w*erev, wd=w}.
// ---------------------------------------------------------------------------
__global__ void prep_kernel(const float* __restrict__ mask,
                            const float* __restrict__ sigma,
                            const float* __restrict__ mu,
                            const float* __restrict__ w_rec,
                            const float* __restrict__ erev,
                            int* __restrict__ slot_src,
                            float4* __restrict__ slot_f4,
                            int* __restrict__ helpers,
                            int* __restrict__ misc)
{
    __shared__ int F[UNITS], lc[UNITS];
    __shared__ unsigned char srcs[UNITS][UNITS];
    __shared__ int dest[64], start[64], cnt[64];
    __shared__ int hl[UNITS][3], hcnt[UNITS];
    __shared__ int share_max_s;
    const int tid = threadIdx.x;   // 64 threads

    if (tid < UNITS) {
        int u = tid, f = 0;
        for (int j = 0; j < UNITS; ++j)
            if (mask[j * UNITS + u] != 0.0f) srcs[u][f++] = (unsigned char)j;
        F[u] = f; lc[u] = 1;
    }
    __syncthreads();

    if (tid == 0) {
        // greedy: hand out the 13 spare lanes to minimize max per-lane share
        for (int sp = 0; sp < 13; ++sp) {
            int best = -1, bv = 1;   // only split outputs with share > 1
            for (int u = 0; u < UNITS; ++u) {
                if (lc[u] >= 4) continue;
                int share = (F[u] + lc[u] - 1) / lc[u];
                if (share > bv) { bv = share; best = u; }
            }
            if (best < 0) break;
            lc[best]++;
        }
        int spare = UNITS, smax = 0;
        for (int l = 0; l < 64; ++l) { dest[l] = -1; start[l] = 0; cnt[l] = 0; }
        for (int u = 0; u < UNITS; ++u) {
            int g = lc[u];
            int share = (F[u] + g - 1) / g;
            if (share > CAP) share = CAP;             // safety clamp (shouldn't fire)
            if (share > smax) smax = share;
            dest[u] = u; start[u] = 0;
            int c0 = share < F[u] ? share : F[u];
            cnt[u] = c0;
            int pos = c0;
            hcnt[u] = 0;
            for (int k = 0; k < g - 1; ++k) {
                int rem = F[u] - pos;
                if (rem <= 0) break;
                int L = spare++;
                hl[u][hcnt[u]++] = L;
                dest[L] = u; start[L] = pos;
                int c = rem < share ? rem : share;
                cnt[L] = c; pos += c;
            }
            for (int k = hcnt[u]; k < 3; ++k) hl[u][k] = 0;
        }
        share_max_s = smax;
    }
    __syncthreads();

    const int l = tid;
    const int d = dest[l];
    for (int s = 0; s < CAP; ++s) {
        int valid = (d >= 0) && (s < cnt[l]);
        int j = valid ? (int)srcs[d][start[l] + s] : 0;
        slot_src[l * CAP + s] = j;
        for (int var = 0; var < VAR_N; ++var) {
            float4 f4 = make_float4(0.f, 0.f, 0.f, 0.f);
            if (valid) {
                int base = (var * UNITS + j) * UNITS + d;
                float sg = sigma[base], m = mu[base];
                float w  = w_rec[base] * mask[j * UNITS + d];
                f4.x = -LOG2E * sg;          // c1
                f4.y =  LOG2E * sg * m;      // c2  (exp2(c1*v+c2) == exp(-sg*(v-m)))
                f4.z =  w * erev[base];      // wn
                f4.w =  w;                   // wd
            }
            slot_f4[(var * 64 + l) * CAP + s] = f4;
        }
    }
    if (l < UNITS) {
        helpers[l * 4 + 0] = hl[l][0];
        helpers[l * 4 + 1] = hl[l][1];
        helpers[l * 4 + 2] = hl[l][2];
        helpers[l * 4 + 3] = hcnt[l];
    } else {
        helpers[l * 4 + 0] = 0; helpers[l * 4 + 1] = 0;
        helpers[l * 4 + 2] = 0; helpers[l * 4 + 3] = 0;
    }
    if (tid == 0) misc[0] = share_max_s;
}

// ---------------------------------------------------------------------------
// Generic Y = act(X @ W.T + b) layer.  X:(N,I) W:(O,I) Y:(N,O).
// 64x64 tile per block, 4x4 register block per thread, K-tiles of 68 in LDS.
// ---------------------------------------------------------------------------
template <int ACT>  // 0 = linear, 1 = sigmoid
__global__ __launch_bounds__(256) void layer_kernel(
    const float* __restrict__ X, const float* __restrict__ W,
    const float* __restrict__ bias, float* __restrict__ Y,
    int N, int I, int O)
{
    const int KT = 68, ST = 73;   // odd LDS stride -> at most 2-way bank aliasing
    __shared__ float Xs[64 * ST];
    __shared__ float Ws[64 * ST];
    const int tid = threadIdx.x;
    const int rb = blockIdx.x * 64, obk = blockIdx.y * 64;
    const int r0 = (tid & 15) * 4, o0 = (tid >> 4) * 4;
    float acc[4][4];
#pragma unroll
    for (int i = 0; i < 4; ++i)
#pragma unroll
        for (int j = 0; j < 4; ++j) acc[i][j] = 0.f;

    for (int k0 = 0; k0 < I; k0 += KT) {
        for (int idx = tid; idx < 64 * KT; idx += 256) {
            int rr = idx / KT, kk = idx - rr * KT;
            int gk = k0 + kk;
            int gr = rb + rr;
            Xs[rr * ST + kk] = (gr < N && gk < I) ? X[(size_t)gr * I + gk] : 0.f;
            int go = obk + rr;
            Ws[rr * ST + kk] = (go < O && gk < I) ? W[(size_t)go * I + gk] : 0.f;
        }
        __syncthreads();
#pragma unroll 4
        for (int k = 0; k < KT; ++k) {
            float xv[4], wv[4];
#pragma unroll
            for (int i = 0; i < 4; ++i) { xv[i] = Xs[(r0 + i) * ST + k]; wv[i] = Ws[(o0 + i) * ST + k]; }
#pragma unroll
            for (int i = 0; i < 4; ++i)
#pragma unroll
                for (int j = 0; j < 4; ++j) acc[i][j] = fmaf(xv[i], wv[j], acc[i][j]);
        }
        __syncthreads();
    }
#pragma unroll
    for (int i = 0; i < 4; ++i) {
        int gr = rb + r0 + i;
        if (gr >= N) continue;
#pragma unroll
        for (int j = 0; j < 4; ++j) {
            int go = obk + o0 + j;
            if (go >= O) continue;
            float yv = acc[i][j] + bias[go];
            if (ACT) yv = __builtin_amdgcn_rcpf(1.0f + __expf(-yv));
            Y[(size_t)gr * O + go] = yv;
        }
    }
}

// ---------------------------------------------------------------------------
// Sensory precompute: for each (t<B, var, u) the input-driven synapse sums
// (state-independent -> hoisted out of the sequential scan).
// ---------------------------------------------------------------------------
__global__ void sensory_kernel(const float* __restrict__ h,
                               const float* __restrict__ ssig,
                               const float* __restrict__ smu,
                               const float* __restrict__ sw,
                               const float* __restrict__ serev,
                               const float* __restrict__ smask,
                               const float* __restrict__ iw,
                               const float* __restrict__ ib,
                               float2* __restrict__ nsden, int Bn)
{
    int idx = blockIdx.x * blockDim.x + threadIdx.x;   // over Bn*4*51
    int total = Bn * VAR_N * UNITS;
    if (idx >= total) return;
    int u = idx % UNITS;
    int tv = idx / UNITS;
    int var = tv & 3;
    int t = tv >> 2;
    const float* hr = h + (size_t)t * 68 + var * LEVELS;
    float num = 0.f, den = 0.f;
#pragma unroll
    for (int s = 0; s < LEVELS; ++s) {
        int bi = (var * LEVELS + s) * UNITS + u;
        float ival = fmaf(hr[s], iw[var * LEVELS + s], ib[var * LEVELS + s]);
        float x = ssig[bi] * (ival - smu[bi]);
        float r = sw[bi] * smask[s * UNITS + u] *
                  __builtin_amdgcn_rcpf(1.0f + __expf(-x));
        num = fmaf(r, serev[bi], num);
        den += r;
    }
    nsden[idx] = make_float2(num, den);
}

// ---------------------------------------------------------------------------
// The sequential scan: one block, 4 waves (wave = variable). State v lives in
// lane u of the wave; cross-unit reads via __shfl (ds_bpermute). No barriers.
// ---------------------------------------------------------------------------
__global__ __launch_bounds__(256, 1) void scan_kernel(
    const int* __restrict__ slot_src, const float4* __restrict__ slot_f4,
    const int* __restrict__ helpers, const int* __restrict__ misc,
    const float2* __restrict__ nsden,
    const float* __restrict__ cm, const float* __restrict__ gleak,
    const float* __restrict__ vleak, const float* __restrict__ ow,
    const float* __restrict__ ob, float* __restrict__ outs, int T, int B)
{
    const int lane = threadIdx.x & 63;
    const int var  = threadIdx.x >> 6;

    int   src[CAP];
    float c1[CAP], c2[CAP], wn[CAP], wd[CAP];
#pragma unroll
    for (int s = 0; s < CAP; ++s) {
        src[s] = slot_src[lane * CAP + s];
        float4 f = slot_f4[(var * 64 + lane) * CAP + s];
        c1[s] = f.x; c2[s] = f.y; wn[s] = f.z; wd[s] = f.w;
    }
    const int h0 = helpers[lane * 4 + 0], h1 = helpers[lane * 4 + 1];
    const int h2 = helpers[lane * 4 + 2], hc = helpers[lane * 4 + 3];
    const int nmax = misc[0];

    const bool prim = lane < UNITS;
    const int  uu = prim ? lane : 0;
    const float cmt  = cm[var * UNITS + uu] * (float)UNFOLDS;
    const float gl   = gleak[var * UNITS + uu];
    const float glvl = gl * vleak[var * UNITS + uu];
    float owv = 0.f, obv = 0.f;
    if (lane < LEVELS) { owv = ow[var * LEVELS + lane]; obv = ob[var * LEVELS + lane]; }

    float v = 0.f;
    float2 cur = make_float2(0.f, 0.f);
    if (prim) cur = nsden[(size_t)(0 * VAR_N + var) * UNITS + lane];

    for (int t = 0; t < T; ++t) {
        int t1 = (t + 1 < B) ? (t + 1) : (B - 1);
        float2 nxt = make_float2(0.f, 0.f);
        if (prim) nxt = nsden[(size_t)(t1 * VAR_N + var) * UNITS + lane];   // prefetch

        for (int k = 0; k < UNFOLDS; ++k) {
            float np = 0.f, dp = 0.f;
#pragma unroll
            for (int s = 0; s < CAP; ++s) {
                if (s < nmax) {
                    float vj = __shfl(v, src[s], 64);
                    float e  = exp2f(fmaf(c1[s], vj, c2[s]));
                    float r  = __builtin_amdgcn_rcpf(1.0f + e);
                    np = fmaf(wn[s], r, np);
                    dp = fmaf(wd[s], r, dp);
                }
            }
            // combine helper-lane partials (spare lanes computing overflow fan-in)
            float an0 = __shfl(np, h0, 64), ad0 = __shfl(dp, h0, 64);
            float an1 = __shfl(np, h1, 64), ad1 = __shfl(dp, h1, 64);
            float an2 = __shfl(np, h2, 64), ad2 = __shfl(dp, h2, 64);
            if (hc > 0) { np += an0; dp += ad0; }
            if (hc > 1) { np += an1; dp += ad1; }
            if (hc > 2) { np += an2; dp += ad2; }

            float num = fmaf(cmt, v, glvl) + np + cur.x;
            float den = cmt + gl + dp + cur.y + 1e-8f;
            float r0 = __builtin_amdgcn_rcpf(den);
            r0 = r0 * (2.0f - den * r0);            // one Newton step -> ~full fp32
            float vn = num * r0;
            if (prim) v = vn;
        }
        if (lane < LEVELS)
            outs[(size_t)(t * VAR_N + var) * LEVELS + lane] = fmaf(v, owv, obv);
        cur = nxt;
    }
}

// ---------------------------------------------------------------------------
extern "C" void kernel_launch(void* const* d_in, const int* in_sizes, int n_in,
                              void* d_out, int out_size, void* d_ws, size_t ws_size,
                              hipStream_t stream)
{
    const float* x     = (const float*)d_in[0];
    const float* pre_W = (const float*)d_in[1];
    const float* pre_b = (const float*)d_in[2];
    const float* gleak = (const float*)d_in[3];
    const float* vleak = (const float*)d_in[4];
    const float* cm    = (const float*)d_in[5];
    const float* sigma = (const float*)d_in[6];
    const float* mu    = (const float*)d_in[7];
    const float* w_rec = (const float*)d_in[8];
    const float* erev  = (const float*)d_in[9];
    const float* ssig  = (const float*)d_in[10];
    const float* smu   = (const float*)d_in[11];
    const float* sw    = (const float*)d_in[12];
    const float* serev = (const float*)d_in[13];
    const float* iw    = (const float*)d_in[14];
    const float* ib    = (const float*)d_in[15];
    const float* ow    = (const float*)d_in[16];
    const float* ob    = (const float*)d_in[17];
    const float* mask  = (const float*)d_in[18];
    const float* smask = (const float*)d_in[19];
    const float* e1W[5] = {(const float*)d_in[20], (const float*)d_in[22],
                           (const float*)d_in[24], (const float*)d_in[26],
                           (const float*)d_in[28]};
    const float* e1b[5] = {(const float*)d_in[21], (const float*)d_in[23],
                           (const float*)d_in[25], (const float*)d_in[27],
                           (const float*)d_in[29]};
    const float* e2W[5] = {(const float*)d_in[30], (const float*)d_in[32],
                           (const float*)d_in[34], (const float*)d_in[36],
                           (const float*)d_in[38]};
    const float* e2b[5] = {(const float*)d_in[31], (const float*)d_in[33],
                           (const float*)d_in[35], (const float*)d_in[37],
                           (const float*)d_in[39]};

    const int B  = in_sizes[0] / 68;      // 32768
    const int T  = B + PRED_N;            // 32796
    const int N1 = T * VAR_N;             // e1 row count

    // workspace layout (fp32 elements); total ~134 MB
    float*  ws    = (float*)d_ws;
    float*  nsden = ws;                                        // B*4*51*2
    float*  outsb = nsden + (size_t)B * VAR_N * UNITS * 2;     // T*4*17
    float*  buf1  = outsb + (size_t)T * VAR_N * LEVELS;        // T*272
    float*  buf2  = buf1 + (size_t)T * 272;                    // T*272
    int*    ssrc  = (int*)(buf2 + (size_t)T * 272);            // 64*CAP
    float4* sf4   = (float4*)(ssrc + 64 * CAP);                // 4*64*CAP
    int*    hlp   = (int*)(sf4 + VAR_N * 64 * CAP);            // 64*4
    int*    misc  = hlp + 64 * 4;                              // 4

    dim3 blk(256);
    auto grid2 = [](int N, int O) { return dim3((N + 63) / 64, (O + 63) / 64); };

    prep_kernel<<<1, 64, 0, stream>>>(mask, sigma, mu, w_rec, erev, ssrc, sf4, hlp, misc);

    // pre-encoder: x -> h (ends in buf2)
    layer_kernel<1><<<grid2(B, 68), blk, 0, stream>>>(x,    pre_W + 0 * 68 * 68, pre_b + 0 * 68, buf2, B, 68, 68);
    layer_kernel<1><<<grid2(B, 68), blk, 0, stream>>>(buf2, pre_W + 1 * 68 * 68, pre_b + 1 * 68, buf1, B, 68, 68);
    layer_kernel<1><<<grid2(B, 68), blk, 0, stream>>>(buf1, pre_W + 2 * 68 * 68, pre_b + 2 * 68, buf2, B, 68, 68);
    layer_kernel<1><<<grid2(B, 68), blk, 0, stream>>>(buf2, pre_W + 3 * 68 * 68, pre_b + 3 * 68, buf1, B, 68, 68);
    layer_kernel<0><<<grid2(B, 68), blk, 0, stream>>>(buf1, pre_W + 4 * 68 * 68, pre_b + 4 * 68, buf2, B, 68, 68);

    // sensory sums for all timesteps (h = buf2)
    {
        long total = (long)B * VAR_N * UNITS;
        int nb = (int)((total + 255) / 256);
        sensory_kernel<<<nb, 256, 0, stream>>>(buf2, ssig, smu, sw, serev, smask, iw, ib,
                                               (float2*)nsden, B);
    }

    // the sequential recurrence (single persistent workgroup)
    scan_kernel<<<1, 256, 0, stream>>>(ssrc, sf4, hlp, misc, (const float2*)nsden,
                                       cm, gleak, vleak, ow, ob, outsb, T, B);

    // e1 encoder on outs as (T*4, 17) rows; final layer sigmoid(linear) -> h1 (T,272) in buf1
    layer_kernel<1><<<grid2(N1, 17), blk, 0, stream>>>(outsb, e1W[0], e1b[0], buf1, N1, 17, 17);
    layer_kernel<1><<<grid2(N1, 17), blk, 0, stream>>>(buf1,  e1W[1], e1b[1], buf2, N1, 17, 17);
    layer_kernel<1><<<grid2(N1, 68), blk, 0, stream>>>(buf2,  e1W[2], e1b[2], buf1, N1, 17, 68);
    layer_kernel<1><<<grid2(N1, 68), blk, 0, stream>>>(buf1,  e1W[3], e1b[3], buf2, N1, 68, 68);
    layer_kernel<1><<<grid2(N1, 68), blk, 0, stream>>>(buf2,  e1W[4], e1b[4], buf1, N1, 68, 68);

    // e2 encoder on h1 as (T, 272) rows -> d_out (T,68)
    layer_kernel<1><<<grid2(T, 272), blk, 0, stream>>>(buf1, e2W[0], e2b[0], buf2, T, 272, 272);
    layer_kernel<1><<<grid2(T, 272), blk, 0, stream>>>(buf2, e2W[1], e2b[1], buf1, T, 272, 272);
    layer_kernel<1><<<grid2(T, 68),  blk, 0, stream>>>(buf1, e2W[2], e2b[2], buf2, T, 272, 68);
    layer_kernel<1><<<grid2(T, 68),  blk, 0, stream>>>(buf2, e2W[3], e2b[3], buf1, T, 68, 68);
    layer_kernel<0><<<grid2(T, 68),  blk, 0, stream>>>(buf1, e2W[4], e2b[4], (float*)d_out, T, 68, 68);
}

// Round 2
// 101934.711 us; speedup vs baseline: 1.7621x; 1.7621x over previous
//
#include <hip/hip_runtime.h>

#define LOG2E   1.4426950408889634f
#define SLOTS   12      // compile-time fan-in slots per lane (branchless)
#define LEVELS  17
#define UNITS   51
#define VAR_N   4
#define PRED_N  28
#define UNFOLDS 6
#define EPS     1e-8f

// DPP quad-perm butterfly helpers (VALU cross-lane, no LDS latency).
// xor1: quad_perm [1,0,3,2] = 0xB1 ; xor2: quad_perm [2,3,0,1] = 0x4E
template <int CTRL>
__device__ __forceinline__ float qp_dpp(float x) {
    int r = __builtin_amdgcn_update_dpp(0, __float_as_int(x), CTRL, 0xF, 0xF, true);
    return __int_as_float(r);
}

// ---------------------------------------------------------------------------
// Prep: data-driven sparse fan-in tables. Units with fan-in F<=12 get 1 lane,
// F<=24 an even-aligned lane pair, F<=48 an aligned quad. Partial np/dp sums
// combine in-kernel via DPP xor1/xor2 masked by lane flags m1/m2.
// ---------------------------------------------------------------------------
__global__ void prep_kernel(const float* __restrict__ mask,
                            const float* __restrict__ sigma,
                            const float* __restrict__ mu,
                            const float* __restrict__ w_rec,
                            const float* __restrict__ erev,
                            int* __restrict__ slot_src,
                            float4* __restrict__ slot_f4,
                            int* __restrict__ lane_u,
                            float* __restrict__ lane_m1,
                            float* __restrict__ lane_m2,
                            int* __restrict__ lane_st)
{
    __shared__ int F[UNITS], g[UNITS], base[UNITS], lu[64];
    __shared__ unsigned char srcs[UNITS][UNITS];
    const int tid = threadIdx.x;   // 64 threads

    if (tid < UNITS) {
        int u = tid, f = 0;
        for (int j = 0; j < UNITS; ++j)
            if (mask[j * UNITS + u] != 0.0f) srcs[u][f++] = (unsigned char)j;
        F[u] = f;
    }
    __syncthreads();

    if (tid == 0) {
        int tot = 0;
        for (int u = 0; u < UNITS; ++u) {
            int gg = (F[u] <= SLOTS) ? 1 : (F[u] <= 2 * SLOTS ? 2 : 4);
            g[u] = gg; tot += gg;
        }
        // fallback demotion (should never trigger for this wiring)
        while (tot > 64) {
            int b = -1, bf = 1 << 30;
            for (int u = 0; u < UNITS; ++u)
                if (g[u] > 1 && F[u] < bf) { bf = F[u]; b = u; }
            if (b < 0) break;
            int old = g[b]; g[b] = old >> 1; tot -= old - g[b];
        }
        int nl = 0;
        for (int u = 0; u < UNITS; ++u) if (g[u] == 4) { base[u] = nl; for (int k = 0; k < 4; ++k) lu[nl + k] = u; nl += 4; }
        for (int u = 0; u < UNITS; ++u) if (g[u] == 2) { base[u] = nl; lu[nl] = u; lu[nl + 1] = u; nl += 2; }
        for (int u = 0; u < UNITS; ++u) if (g[u] == 1) { base[u] = nl; lu[nl] = u; nl += 1; }
        for (; nl < 64; ++nl) lu[nl] = -1;
    }
    __syncthreads();

    const int l = tid;
    const int u = lu[l];
    int lo = 0, hi = 0, m1 = 0, m2 = 0, st = 0;
    if (u >= 0) {
        int gg = g[u];
        m1 = gg >= 2; m2 = gg == 4;
        st = (u < LEVELS) && (l == base[u]);
        int share = (F[u] + gg - 1) / gg;
        int k = l - base[u];
        lo = k * share;
        hi = F[u] < lo + share ? F[u] : lo + share;
    }
    lane_u[l]  = (u >= 0) ? u : 0;
    lane_m1[l] = (float)m1;
    lane_m2[l] = (float)m2;
    lane_st[l] = st;

    for (int s = 0; s < SLOTS; ++s) {
        int valid = (u >= 0) && (lo + s < hi);
        int j = valid ? (int)srcs[u][lo + s] : 0;
        slot_src[l * SLOTS + s] = valid ? base[j] : 0;
        for (int var = 0; var < VAR_N; ++var) {
            float4 f4 = make_float4(0.f, 0.f, 0.f, 0.f);
            if (valid) {
                int bi = (var * UNITS + j) * UNITS + u;
                float sg = sigma[bi], m = mu[bi];
                float w  = w_rec[bi] * mask[j * UNITS + u];
                f4.x = -LOG2E * sg;          // c1
                f4.y =  LOG2E * sg * m;      // c2  (exp2(c1*v+c2) == exp(-sg*(v-m)))
                f4.z =  w * erev[bi];        // wn
                f4.w =  w;                   // wd
            }
            slot_f4[(var * 64 + l) * SLOTS + s] = f4;
        }
    }
}

// ---------------------------------------------------------------------------
// Generic Y = act(X @ W.T + b) layer.  X:(N,I) W:(O,I) Y:(N,O).
// ---------------------------------------------------------------------------
template <int ACT>  // 0 = linear, 1 = sigmoid
__global__ __launch_bounds__(256) void layer_kernel(
    const float* __restrict__ X, const float* __restrict__ W,
    const float* __restrict__ bias, float* __restrict__ Y,
    int N, int I, int O)
{
    const int KT = 68, ST = 73;
    __shared__ float Xs[64 * ST];
    __shared__ float Ws[64 * ST];
    const int tid = threadIdx.x;
    const int rb = blockIdx.x * 64, obk = blockIdx.y * 64;
    const int r0 = (tid & 15) * 4, o0 = (tid >> 4) * 4;
    float acc[4][4];
#pragma unroll
    for (int i = 0; i < 4; ++i)
#pragma unroll
        for (int j = 0; j < 4; ++j) acc[i][j] = 0.f;

    for (int k0 = 0; k0 < I; k0 += KT) {
        for (int idx = tid; idx < 64 * KT; idx += 256) {
            int rr = idx / KT, kk = idx - rr * KT;
            int gk = k0 + kk;
            int gr = rb + rr;
            Xs[rr * ST + kk] = (gr < N && gk < I) ? X[(size_t)gr * I + gk] : 0.f;
            int go = obk + rr;
            Ws[rr * ST + kk] = (go < O && gk < I) ? W[(size_t)go * I + gk] : 0.f;
        }
        __syncthreads();
#pragma unroll 4
        for (int k = 0; k < KT; ++k) {
            float xv[4], wv[4];
#pragma unroll
            for (int i = 0; i < 4; ++i) { xv[i] = Xs[(r0 + i) * ST + k]; wv[i] = Ws[(o0 + i) * ST + k]; }
#pragma unroll
            for (int i = 0; i < 4; ++i)
#pragma unroll
                for (int j = 0; j < 4; ++j) acc[i][j] = fmaf(xv[i], wv[j], acc[i][j]);
        }
        __syncthreads();
    }
#pragma unroll
    for (int i = 0; i < 4; ++i) {
        int gr = rb + r0 + i;
        if (gr >= N) continue;
#pragma unroll
        for (int j = 0; j < 4; ++j) {
            int go = obk + o0 + j;
            if (go >= O) continue;
            float yv = acc[i][j] + bias[go];
            if (ACT) yv = __builtin_amdgcn_rcpf(1.0f + __expf(-yv));
            Y[(size_t)gr * O + go] = yv;
        }
    }
}

// ---------------------------------------------------------------------------
// Sensory precompute (state-independent, hoisted out of the scan).
// ---------------------------------------------------------------------------
__global__ void sensory_kernel(const float* __restrict__ h,
                               const float* __restrict__ ssig,
                               const float* __restrict__ smu,
                               const float* __restrict__ sw,
                               const float* __restrict__ serev,
                               const float* __restrict__ smask,
                               const float* __restrict__ iw,
                               const float* __restrict__ ib,
                               float2* __restrict__ nsden, int Bn)
{
    int idx = blockIdx.x * blockDim.x + threadIdx.x;
    int total = Bn * VAR_N * UNITS;
    if (idx >= total) return;
    int u = idx % UNITS;
    int tv = idx / UNITS;
    int var = tv & 3;
    int t = tv >> 2;
    const float* hr = h + (size_t)t * 68 + var * LEVELS;
    float num = 0.f, den = 0.f;
#pragma unroll
    for (int s = 0; s < LEVELS; ++s) {
        int bi = (var * LEVELS + s) * UNITS + u;
        float ival = fmaf(hr[s], iw[var * LEVELS + s], ib[var * LEVELS + s]);
        float x = ssig[bi] * (ival - smu[bi]);
        float r = sw[bi] * smask[s * UNITS + u] *
                  __builtin_amdgcn_rcpf(1.0f + __expf(-x));
        num = fmaf(r, serev[bi], num);
        den += r;
    }
    nsden[idx] = make_float2(num, den);
}

// ---------------------------------------------------------------------------
// Sequential scan: 4 blocks (one wave per variable). Branchless 12-slot fan-in
// (one batched bpermute wait per unfold) + DPP butterfly combine (no 2nd LDS
// round-trip).
// ---------------------------------------------------------------------------
__global__ __launch_bounds__(64, 1) void scan_kernel(
    const int* __restrict__ slot_src, const float4* __restrict__ slot_f4,
    const int* __restrict__ lane_u_g, const float* __restrict__ lane_m1_g,
    const float* __restrict__ lane_m2_g, const int* __restrict__ lane_st_g,
    const float2* __restrict__ nsden,
    const float* __restrict__ cm, const float* __restrict__ gleak,
    const float* __restrict__ vleak, const float* __restrict__ ow,
    const float* __restrict__ ob, float* __restrict__ outs, int T, int B)
{
    const int lane = threadIdx.x;
    const int var  = blockIdx.x;

    int   src[SLOTS];
    float c1[SLOTS], c2[SLOTS], wn[SLOTS], wd[SLOTS];
#pragma unroll
    for (int s = 0; s < SLOTS; ++s) {
        src[s] = slot_src[lane * SLOTS + s];
        float4 f = slot_f4[(var * 64 + lane) * SLOTS + s];
        c1[s] = f.x; c2[s] = f.y; wn[s] = f.z; wd[s] = f.w;
    }
    const int   u  = lane_u_g[lane];
    const float m1 = lane_m1_g[lane];
    const float m2 = lane_m2_g[lane];
    const int   st = lane_st_g[lane];

    const float cmt  = cm[var * UNITS + u] * (float)UNFOLDS;
    const float gl   = gleak[var * UNITS + u];
    const float glvl = gl * vleak[var * UNITS + u];
    const float denc = cmt + gl + EPS;
    const float owv  = (u < LEVELS) ? ow[var * LEVELS + u] : 0.f;
    const float obv  = (u < LEVELS) ? ob[var * LEVELS + u] : 0.f;

    float v = 0.f;
    float2 cur = nsden[(size_t)(0 * VAR_N + var) * UNITS + u];

    for (int t = 0; t < T; ++t) {
        int t1 = (t + 1 < B) ? (t + 1) : (B - 1);
        float2 nxt = nsden[(size_t)(t1 * VAR_N + var) * UNITS + u];   // prefetch
        float cnum = glvl + cur.x;
        float cden = denc + cur.y;

#pragma unroll
        for (int k = 0; k < UNFOLDS; ++k) {
            float npa = 0.f, npb = 0.f, dpa = 0.f, dpb = 0.f;
#pragma unroll
            for (int s = 0; s < SLOTS; ++s) {
                float vj = __shfl(v, src[s], 64);
                float e  = exp2f(fmaf(c1[s], vj, c2[s]));
                float r  = __builtin_amdgcn_rcpf(1.0f + e);
                if (s & 1) { npb = fmaf(wn[s], r, npb); dpb = fmaf(wd[s], r, dpb); }
                else       { npa = fmaf(wn[s], r, npa); dpa = fmaf(wd[s], r, dpa); }
            }
            float np = npa + npb, dp = dpa + dpb;
            np = fmaf(m1, qp_dpp<0xB1>(np), np);   // pair combine (xor1)
            dp = fmaf(m1, qp_dpp<0xB1>(dp), dp);
            np = fmaf(m2, qp_dpp<0x4E>(np), np);   // quad combine (xor2)
            dp = fmaf(m2, qp_dpp<0x4E>(dp), dp);

            float num = fmaf(cmt, v, cnum) + np;
            float den = cden + dp;
            float r0 = __builtin_amdgcn_rcpf(den);
            r0 = r0 * (2.0f - den * r0);            // one Newton step
            v = num * r0;
        }
        if (st) outs[(size_t)(t * VAR_N + var) * LEVELS + u] = fmaf(v, owv, obv);
        cur = nxt;
    }
}

// ---------------------------------------------------------------------------
extern "C" void kernel_launch(void* const* d_in, const int* in_sizes, int n_in,
                              void* d_out, int out_size, void* d_ws, size_t ws_size,
                              hipStream_t stream)
{
    const float* x     = (const float*)d_in[0];
    const float* pre_W = (const float*)d_in[1];
    const float* pre_b = (const float*)d_in[2];
    const float* gleak = (const float*)d_in[3];
    const float* vleak = (const float*)d_in[4];
    const float* cm    = (const float*)d_in[5];
    const float* sigma = (const float*)d_in[6];
    const float* mu    = (const float*)d_in[7];
    const float* w_rec = (const float*)d_in[8];
    const float* erev  = (const float*)d_in[9];
    const float* ssig  = (const float*)d_in[10];
    const float* smu   = (const float*)d_in[11];
    const float* sw    = (const float*)d_in[12];
    const float* serev = (const float*)d_in[13];
    const float* iw    = (const float*)d_in[14];
    const float* ib    = (const float*)d_in[15];
    const float* ow    = (const float*)d_in[16];
    const float* ob    = (const float*)d_in[17];
    const float* mask  = (const float*)d_in[18];
    const float* smask = (const float*)d_in[19];
    const float* e1W[5] = {(const float*)d_in[20], (const float*)d_in[22],
                           (const float*)d_in[24], (const float*)d_in[26],
                           (const float*)d_in[28]};
    const float* e1b[5] = {(const float*)d_in[21], (const float*)d_in[23],
                           (const float*)d_in[25], (const float*)d_in[27],
                           (const float*)d_in[29]};
    const float* e2W[5] = {(const float*)d_in[30], (const float*)d_in[32],
                           (const float*)d_in[34], (const float*)d_in[36],
                           (const float*)d_in[38]};
    const float* e2b[5] = {(const float*)d_in[31], (const float*)d_in[33],
                           (const float*)d_in[35], (const float*)d_in[37],
                           (const float*)d_in[39]};

    const int B  = in_sizes[0] / 68;      // 32768
    const int T  = B + PRED_N;            // 32796
    const int N1 = T * VAR_N;

    // workspace layout (fp32 elements)
    float*  ws    = (float*)d_ws;
    float*  nsden = ws;                                        // B*4*51*2
    float*  outsb = nsden + (size_t)B * VAR_N * UNITS * 2;     // T*4*17
    float*  buf1  = outsb + (size_t)T * VAR_N * LEVELS;        // T*272
    float*  buf2  = buf1 + (size_t)T * 272;                    // T*272
    int*    ssrc  = (int*)(buf2 + (size_t)T * 272);            // 64*SLOTS
    float4* sf4   = (float4*)(ssrc + 64 * SLOTS);              // 4*64*SLOTS
    int*    lu    = (int*)(sf4 + VAR_N * 64 * SLOTS);          // 64
    float*  lm1   = (float*)(lu + 64);                         // 64
    float*  lm2   = lm1 + 64;                                  // 64
    int*    lst   = (int*)(lm2 + 64);                          // 64

    dim3 blk(256);
    auto grid2 = [](int N, int O) { return dim3((N + 63) / 64, (O + 63) / 64); };

    prep_kernel<<<1, 64, 0, stream>>>(mask, sigma, mu, w_rec, erev,
                                      ssrc, sf4, lu, lm1, lm2, lst);

    // pre-encoder: x -> h (ends in buf2)
    layer_kernel<1><<<grid2(B, 68), blk, 0, stream>>>(x,    pre_W + 0 * 68 * 68, pre_b + 0 * 68, buf2, B, 68, 68);
    layer_kernel<1><<<grid2(B, 68), blk, 0, stream>>>(buf2, pre_W + 1 * 68 * 68, pre_b + 1 * 68, buf1, B, 68, 68);
    layer_kernel<1><<<grid2(B, 68), blk, 0, stream>>>(buf1, pre_W + 2 * 68 * 68, pre_b + 2 * 68, buf2, B, 68, 68);
    layer_kernel<1><<<grid2(B, 68), blk, 0, stream>>>(buf2, pre_W + 3 * 68 * 68, pre_b + 3 * 68, buf1, B, 68, 68);
    layer_kernel<0><<<grid2(B, 68), blk, 0, stream>>>(buf1, pre_W + 4 * 68 * 68, pre_b + 4 * 68, buf2, B, 68, 68);

    {
        long total = (long)B * VAR_N * UNITS;
        int nb = (int)((total + 255) / 256);
        sensory_kernel<<<nb, 256, 0, stream>>>(buf2, ssig, smu, sw, serev, smask, iw, ib,
                                               (float2*)nsden, B);
    }

    // the sequential recurrence: one wave per variable, each on its own CU
    scan_kernel<<<dim3(VAR_N), 64, 0, stream>>>(ssrc, sf4, lu, lm1, lm2, lst,
                                                (const float2*)nsden,
                                                cm, gleak, vleak, ow, ob, outsb, T, B);

    // e1 encoder on outs as (T*4, 17) rows -> h1 (T,272) in buf1
    layer_kernel<1><<<grid2(N1, 17), blk, 0, stream>>>(outsb, e1W[0], e1b[0], buf1, N1, 17, 17);
    layer_kernel<1><<<grid2(N1, 17), blk, 0, stream>>>(buf1,  e1W[1], e1b[1], buf2, N1, 17, 17);
    layer_kernel<1><<<grid2(N1, 68), blk, 0, stream>>>(buf2,  e1W[2], e1b[2], buf1, N1, 17, 68);
    layer_kernel<1><<<grid2(N1, 68), blk, 0, stream>>>(buf1,  e1W[3], e1b[3], buf2, N1, 68, 68);
    layer_kernel<1><<<grid2(N1, 68), blk, 0, stream>>>(buf2,  e1W[4], e1b[4], buf1, N1, 68, 68);

    // e2 encoder on h1 as (T, 272) rows -> d_out (T,68)
    layer_kernel<1><<<grid2(T, 272), blk, 0, stream>>>(buf1, e2W[0], e2b[0], buf2, T, 272, 272);
    layer_kernel<1><<<grid2(T, 272), blk, 0, stream>>>(buf2, e2W[1], e2b[1], buf1, T, 272, 272);
    layer_kernel<1><<<grid2(T, 68),  blk, 0, stream>>>(buf1, e2W[2], e2b[2], buf2, T, 272, 68);
    layer_kernel<1><<<grid2(T, 68),  blk, 0, stream>>>(buf2, e2W[3], e2b[3], buf1, T, 68, 68);
    layer_kernel<0><<<grid2(T, 68),  blk, 0, stream>>>(buf1, e2W[4], e2b[4], (float*)d_out, T, 68, 68);
}

// Round 10
// 88199.304 us; speedup vs baseline: 2.0365x; 1.1557x over previous
//
#include <hip/hip_runtime.h>

#define LOG2E   1.4426950408889634f
#define SLOTS   12      // compile-time fan-in slots per lane (branchless)
#define LEVELS  17
#define UNITS   51
#define VAR_N   4
#define PRED_N  28
#define UNFOLDS 6
#define EPS     1e-8f

// DPP quad-perm butterfly helpers (VALU cross-lane, no LDS latency).
// xor1: quad_perm [1,0,3,2] = 0xB1 ; xor2: quad_perm [2,3,0,1] = 0x4E
template <int CTRL>
__device__ __forceinline__ float qp_dpp(float x) {
    int r = __builtin_amdgcn_update_dpp(0, __float_as_int(x), CTRL, 0xF, 0xF, true);
    return __int_as_float(r);
}

// ---------------------------------------------------------------------------
// Prep: data-driven sparse fan-in tables. Units with fan-in F<=12 get 1 lane,
// F<=24 an even-aligned lane pair, F<=48 an aligned quad. Partial np/dp sums
// combine in-kernel via DPP xor1/xor2 masked by lane flags m1/m2.
// ---------------------------------------------------------------------------
__global__ void prep_kernel(const float* __restrict__ mask,
                            const float* __restrict__ sigma,
                            const float* __restrict__ mu,
                            const float* __restrict__ w_rec,
                            const float* __restrict__ erev,
                            int* __restrict__ slot_src,
                            float4* __restrict__ slot_f4,
                            int* __restrict__ lane_u,
                            float* __restrict__ lane_m1,
                            float* __restrict__ lane_m2,
                            int* __restrict__ lane_st)
{
    __shared__ int F[UNITS], g[UNITS], base[UNITS], lu[64];
    __shared__ unsigned char srcs[UNITS][UNITS];
    const int tid = threadIdx.x;   // 64 threads

    if (tid < UNITS) {
        int u = tid, f = 0;
        for (int j = 0; j < UNITS; ++j)
            if (mask[j * UNITS + u] != 0.0f) srcs[u][f++] = (unsigned char)j;
        F[u] = f;
    }
    __syncthreads();

    if (tid == 0) {
        int tot = 0;
        for (int u = 0; u < UNITS; ++u) {
            int gg = (F[u] <= SLOTS) ? 1 : (F[u] <= 2 * SLOTS ? 2 : 4);
            g[u] = gg; tot += gg;
        }
        while (tot > 64) {
            int b = -1, bf = 1 << 30;
            for (int u = 0; u < UNITS; ++u)
                if (g[u] > 1 && F[u] < bf) { bf = F[u]; b = u; }
            if (b < 0) break;
            int old = g[b]; g[b] = old >> 1; tot -= old - g[b];
        }
        int nl = 0;
        for (int u = 0; u < UNITS; ++u) if (g[u] == 4) { base[u] = nl; for (int k = 0; k < 4; ++k) lu[nl + k] = u; nl += 4; }
        for (int u = 0; u < UNITS; ++u) if (g[u] == 2) { base[u] = nl; lu[nl] = u; lu[nl + 1] = u; nl += 2; }
        for (int u = 0; u < UNITS; ++u) if (g[u] == 1) { base[u] = nl; lu[nl] = u; nl += 1; }
        for (; nl < 64; ++nl) lu[nl] = -1;
    }
    __syncthreads();

    const int l = tid;
    const int u = lu[l];
    int lo = 0, hi = 0, m1 = 0, m2 = 0, st = 0;
    if (u >= 0) {
        int gg = g[u];
        m1 = gg >= 2; m2 = gg == 4;
        st = (u < LEVELS) && (l == base[u]);
        int share = (F[u] + gg - 1) / gg;
        int k = l - base[u];
        lo = k * share;
        hi = F[u] < lo + share ? F[u] : lo + share;
    }
    lane_u[l]  = (u >= 0) ? u : 0;
    lane_m1[l] = (float)m1;
    lane_m2[l] = (float)m2;
    lane_st[l] = st;

    for (int s = 0; s < SLOTS; ++s) {
        int valid = (u >= 0) && (lo + s < hi);
        int j = valid ? (int)srcs[u][lo + s] : 0;
        slot_src[l * SLOTS + s] = valid ? base[j] : 0;
        for (int var = 0; var < VAR_N; ++var) {
            float4 f4 = make_float4(0.f, 0.f, 0.f, 0.f);
            if (valid) {
                int bi = (var * UNITS + j) * UNITS + u;
                float sg = sigma[bi], m = mu[bi];
                float w  = w_rec[bi] * mask[j * UNITS + u];
                f4.x = -LOG2E * sg;          // c1
                f4.y =  LOG2E * sg * m;      // c2  (exp2(c1*v+c2) == exp(-sg*(v-m)))
                f4.z =  w * erev[bi];        // wn
                f4.w =  w;                   // wd
            }
            slot_f4[(var * 64 + l) * SLOTS + s] = f4;
        }
    }
}

// ---------------------------------------------------------------------------
// Generic Y = act(X @ W.T + b) layer.  X:(N,I) W:(O,I) Y:(N,O).
// ---------------------------------------------------------------------------
template <int ACT>  // 0 = linear, 1 = sigmoid
__global__ __launch_bounds__(256) void layer_kernel(
    const float* __restrict__ X, const float* __restrict__ W,
    const float* __restrict__ bias, float* __restrict__ Y,
    int N, int I, int O)
{
    const int KT = 68, ST = 73;
    __shared__ float Xs[64 * ST];
    __shared__ float Ws[64 * ST];
    const int tid = threadIdx.x;
    const int rb = blockIdx.x * 64, obk = blockIdx.y * 64;
    const int r0 = (tid & 15) * 4, o0 = (tid >> 4) * 4;
    float acc[4][4];
#pragma unroll
    for (int i = 0; i < 4; ++i)
#pragma unroll
        for (int j = 0; j < 4; ++j) acc[i][j] = 0.f;

    for (int k0 = 0; k0 < I; k0 += KT) {
        for (int idx = tid; idx < 64 * KT; idx += 256) {
            int rr = idx / KT, kk = idx - rr * KT;
            int gk = k0 + kk;
            int gr = rb + rr;
            Xs[rr * ST + kk] = (gr < N && gk < I) ? X[(size_t)gr * I + gk] : 0.f;
            int go = obk + rr;
            Ws[rr * ST + kk] = (go < O && gk < I) ? W[(size_t)go * I + gk] : 0.f;
        }
        __syncthreads();
#pragma unroll 4
        for (int k = 0; k < KT; ++k) {
            float xv[4], wv[4];
#pragma unroll
            for (int i = 0; i < 4; ++i) { xv[i] = Xs[(r0 + i) * ST + k]; wv[i] = Ws[(o0 + i) * ST + k]; }
#pragma unroll
            for (int i = 0; i < 4; ++i)
#pragma unroll
                for (int j = 0; j < 4; ++j) acc[i][j] = fmaf(xv[i], wv[j], acc[i][j]);
        }
        __syncthreads();
    }
#pragma unroll
    for (int i = 0; i < 4; ++i) {
        int gr = rb + r0 + i;
        if (gr >= N) continue;
#pragma unroll
        for (int j = 0; j < 4; ++j) {
            int go = obk + o0 + j;
            if (go >= O) continue;
            float yv = acc[i][j] + bias[go];
            if (ACT) yv = __builtin_amdgcn_rcpf(1.0f + __expf(-yv));
            Y[(size_t)gr * O + go] = yv;
        }
    }
}

// ---------------------------------------------------------------------------
// Sensory precompute (state-independent, hoisted out of the scan).
// ---------------------------------------------------------------------------
__global__ void sensory_kernel(const float* __restrict__ h,
                               const float* __restrict__ ssig,
                               const float* __restrict__ smu,
                               const float* __restrict__ sw,
                               const float* __restrict__ serev,
                               const float* __restrict__ smask,
                               const float* __restrict__ iw,
                               const float* __restrict__ ib,
                               float2* __restrict__ nsden, int Bn)
{
    int idx = blockIdx.x * blockDim.x + threadIdx.x;
    int total = Bn * VAR_N * UNITS;
    if (idx >= total) return;
    int u = idx % UNITS;
    int tv = idx / UNITS;
    int var = tv & 3;
    int t = tv >> 2;
    const float* hr = h + (size_t)t * 68 + var * LEVELS;
    float num = 0.f, den = 0.f;
#pragma unroll
    for (int s = 0; s < LEVELS; ++s) {
        int bi = (var * LEVELS + s) * UNITS + u;
        float ival = fmaf(hr[s], iw[var * LEVELS + s], ib[var * LEVELS + s]);
        float x = ssig[bi] * (ival - smu[bi]);
        float r = sw[bi] * smask[s * UNITS + u] *
                  __builtin_amdgcn_rcpf(1.0f + __expf(-x));
        num = fmaf(r, serev[bi], num);
        den += r;
    }
    nsden[idx] = make_float2(num, den);
}

// ---------------------------------------------------------------------------
// Sequential scan: 4 blocks (one wave per variable). All slot constants live
// in NAMED scalar registers (no arrays -> no scratch), bpermute addresses
// precomputed in bytes, one batched lgkm wait per unfold, DPP combine.
// ---------------------------------------------------------------------------
#define DECL_SLOT(i)  int a##i; float c1_##i, c2_##i, wn_##i, wd_##i;
#define LOAD_SLOT(i)  { a##i = slot_src[lane * SLOTS + i] * 4;                         \
                        float4 f = slot_f4[(var * 64 + lane) * SLOTS + i];             \
                        c1_##i = f.x; c2_##i = f.y; wn_##i = f.z; wd_##i = f.w; }
#define EVAL_SLOT(i)  { float vj = __int_as_float(                                     \
                            __builtin_amdgcn_ds_bpermute(a##i, __float_as_int(v)));    \
                        float e  = exp2f(fmaf(c1_##i, vj, c2_##i));                    \
                        float r  = __builtin_amdgcn_rcpf(1.0f + e);                    \
                        if (i & 1) { npb = fmaf(wn_##i, r, npb); dpb = fmaf(wd_##i, r, dpb); } \
                        else       { npa = fmaf(wn_##i, r, npa); dpa = fmaf(wd_##i, r, dpa); } }

__global__ __launch_bounds__(64, 1) void scan_kernel(
    const int* __restrict__ slot_src, const float4* __restrict__ slot_f4,
    const int* __restrict__ lane_u_g, const float* __restrict__ lane_m1_g,
    const float* __restrict__ lane_m2_g, const int* __restrict__ lane_st_g,
    const float2* __restrict__ nsden,
    const float* __restrict__ cm, const float* __restrict__ gleak,
    const float* __restrict__ vleak, const float* __restrict__ ow,
    const float* __restrict__ ob, float* __restrict__ outs, int T, int B)
{
    const int lane = threadIdx.x;
    const int var  = blockIdx.x;

    DECL_SLOT(0)  DECL_SLOT(1)  DECL_SLOT(2)  DECL_SLOT(3)
    DECL_SLOT(4)  DECL_SLOT(5)  DECL_SLOT(6)  DECL_SLOT(7)
    DECL_SLOT(8)  DECL_SLOT(9)  DECL_SLOT(10) DECL_SLOT(11)
    LOAD_SLOT(0)  LOAD_SLOT(1)  LOAD_SLOT(2)  LOAD_SLOT(3)
    LOAD_SLOT(4)  LOAD_SLOT(5)  LOAD_SLOT(6)  LOAD_SLOT(7)
    LOAD_SLOT(8)  LOAD_SLOT(9)  LOAD_SLOT(10) LOAD_SLOT(11)

    const int   u  = lane_u_g[lane];
    const float m1 = lane_m1_g[lane];
    const float m2 = lane_m2_g[lane];
    const int   st = lane_st_g[lane];

    const float cmt  = cm[var * UNITS + u] * (float)UNFOLDS;
    const float gl   = gleak[var * UNITS + u];
    const float glvl = gl * vleak[var * UNITS + u];
    const float denc = cmt + gl + EPS;
    const float owv  = (u < LEVELS) ? ow[var * LEVELS + u] : 0.f;
    const float obv  = (u < LEVELS) ? ob[var * LEVELS + u] : 0.f;

    float v = 0.f;
    float2 cur = nsden[(size_t)(0 * VAR_N + var) * UNITS + u];

    for (int t = 0; t < T; ++t) {
        int t1 = (t + 1 < B) ? (t + 1) : (B - 1);
        float2 nxt = nsden[(size_t)(t1 * VAR_N + var) * UNITS + u];   // prefetch
        float cnum = glvl + cur.x;
        float cden = denc + cur.y;

#pragma unroll
        for (int k = 0; k < UNFOLDS; ++k) {
            float npa = 0.f, npb = 0.f, dpa = 0.f, dpb = 0.f;
            EVAL_SLOT(0)  EVAL_SLOT(1)  EVAL_SLOT(2)  EVAL_SLOT(3)
            EVAL_SLOT(4)  EVAL_SLOT(5)  EVAL_SLOT(6)  EVAL_SLOT(7)
            EVAL_SLOT(8)  EVAL_SLOT(9)  EVAL_SLOT(10) EVAL_SLOT(11)
            float np = npa + npb, dp = dpa + dpb;
            np = fmaf(m1, qp_dpp<0xB1>(np), np);   // pair combine (xor1)
            dp = fmaf(m1, qp_dpp<0xB1>(dp), dp);
            np = fmaf(m2, qp_dpp<0x4E>(np), np);   // quad combine (xor2)
            dp = fmaf(m2, qp_dpp<0x4E>(dp), dp);

            float num = fmaf(cmt, v, cnum) + np;
            float den = cden + dp;
            float r0 = __builtin_amdgcn_rcpf(den);
            r0 = r0 * (2.0f - den * r0);            // one Newton step
            v = num * r0;
        }
        if (st) outs[(size_t)(t * VAR_N + var) * LEVELS + u] = fmaf(v, owv, obv);
        cur = nxt;
    }
}

// ---------------------------------------------------------------------------
extern "C" void kernel_launch(void* const* d_in, const int* in_sizes, int n_in,
                              void* d_out, int out_size, void* d_ws, size_t ws_size,
                              hipStream_t stream)
{
    const float* x     = (const float*)d_in[0];
    const float* pre_W = (const float*)d_in[1];
    const float* pre_b = (const float*)d_in[2];
    const float* gleak = (const float*)d_in[3];
    const float* vleak = (const float*)d_in[4];
    const float* cm    = (const float*)d_in[5];
    const float* sigma = (const float*)d_in[6];
    const float* mu    = (const float*)d_in[7];
    const float* w_rec = (const float*)d_in[8];
    const float* erev  = (const float*)d_in[9];
    const float* ssig  = (const float*)d_in[10];
    const float* smu   = (const float*)d_in[11];
    const float* sw    = (const float*)d_in[12];
    const float* serev = (const float*)d_in[13];
    const float* iw    = (const float*)d_in[14];
    const float* ib    = (const float*)d_in[15];
    const float* ow    = (const float*)d_in[16];
    const float* ob    = (const float*)d_in[17];
    const float* mask  = (const float*)d_in[18];
    const float* smask = (const float*)d_in[19];
    const float* e1W[5] = {(const float*)d_in[20], (const float*)d_in[22],
                           (const float*)d_in[24], (const float*)d_in[26],
                           (const float*)d_in[28]};
    const float* e1b[5] = {(const float*)d_in[21], (const float*)d_in[23],
                           (const float*)d_in[25], (const float*)d_in[27],
                           (const float*)d_in[29]};
    const float* e2W[5] = {(const float*)d_in[30], (const float*)d_in[32],
                           (const float*)d_in[34], (const float*)d_in[36],
                           (const float*)d_in[38]};
    const float* e2b[5] = {(const float*)d_in[31], (const float*)d_in[33],
                           (const float*)d_in[35], (const float*)d_in[37],
                           (const float*)d_in[39]};

    const int B  = in_sizes[0] / 68;      // 32768
    const int T  = B + PRED_N;            // 32796
    const int N1 = T * VAR_N;

    // workspace layout (fp32 elements)
    float*  ws    = (float*)d_ws;
    float*  nsden = ws;                                        // B*4*51*2
    float*  outsb = nsden + (size_t)B * VAR_N * UNITS * 2;     // T*4*17
    float*  buf1  = outsb + (size_t)T * VAR_N * LEVELS;        // T*272
    float*  buf2  = buf1 + (size_t)T * 272;                    // T*272
    int*    ssrc  = (int*)(buf2 + (size_t)T * 272);            // 64*SLOTS
    float4* sf4   = (float4*)(ssrc + 64 * SLOTS);              // 4*64*SLOTS
    int*    lu    = (int*)(sf4 + VAR_N * 64 * SLOTS);          // 64
    float*  lm1   = (float*)(lu + 64);                         // 64
    float*  lm2   = lm1 + 64;                                  // 64
    int*    lst   = (int*)(lm2 + 64);                          // 64

    dim3 blk(256);
    auto grid2 = [](int N, int O) { return dim3((N + 63) / 64, (O + 63) / 64); };

    prep_kernel<<<1, 64, 0, stream>>>(mask, sigma, mu, w_rec, erev,
                                      ssrc, sf4, lu, lm1, lm2, lst);

    // pre-encoder: x -> h (ends in buf2)
    layer_kernel<1><<<grid2(B, 68), blk, 0, stream>>>(x,    pre_W + 0 * 68 * 68, pre_b + 0 * 68, buf2, B, 68, 68);
    layer_kernel<1><<<grid2(B, 68), blk, 0, stream>>>(buf2, pre_W + 1 * 68 * 68, pre_b + 1 * 68, buf1, B, 68, 68);
    layer_kernel<1><<<grid2(B, 68), blk, 0, stream>>>(buf1, pre_W + 2 * 68 * 68, pre_b + 2 * 68, buf2, B, 68, 68);
    layer_kernel<1><<<grid2(B, 68), blk, 0, stream>>>(buf2, pre_W + 3 * 68 * 68, pre_b + 3 * 68, buf1, B, 68, 68);
    layer_kernel<0><<<grid2(B, 68), blk, 0, stream>>>(buf1, pre_W + 4 * 68 * 68, pre_b + 4 * 68, buf2, B, 68, 68);

    {
        long total = (long)B * VAR_N * UNITS;
        int nb = (int)((total + 255) / 256);
        sensory_kernel<<<nb, 256, 0, stream>>>(buf2, ssig, smu, sw, serev, smask, iw, ib,
                                               (float2*)nsden, B);
    }

    // the sequential recurrence: one wave per variable, each on its own CU
    scan_kernel<<<dim3(VAR_N), 64, 0, stream>>>(ssrc, sf4, lu, lm1, lm2, lst,
                                                (const float2*)nsden,
                                                cm, gleak, vleak, ow, ob, outsb, T, B);

    // e1 encoder on outs as (T*4, 17) rows -> h1 (T,272) in buf1
    layer_kernel<1><<<grid2(N1, 17), blk, 0, stream>>>(outsb, e1W[0], e1b[0], buf1, N1, 17, 17);
    layer_kernel<1><<<grid2(N1, 17), blk, 0, stream>>>(buf1,  e1W[1], e1b[1], buf2, N1, 17, 17);
    layer_kernel<1><<<grid2(N1, 68), blk, 0, stream>>>(buf2,  e1W[2], e1b[2], buf1, N1, 17, 68);
    layer_kernel<1><<<grid2(N1, 68), blk, 0, stream>>>(buf1,  e1W[3], e1b[3], buf2, N1, 68, 68);
    layer_kernel<1><<<grid2(N1, 68), blk, 0, stream>>>(buf2,  e1W[4], e1b[4], buf1, N1, 68, 68);

    // e2 encoder on h1 as (T, 272) rows -> d_out (T,68)
    layer_kernel<1><<<grid2(T, 272), blk, 0, stream>>>(buf1, e2W[0], e2b[0], buf2, T, 272, 272);
    layer_kernel<1><<<grid2(T, 272), blk, 0, stream>>>(buf2, e2W[1], e2b[1], buf1, T, 272, 272);
    layer_kernel<1><<<grid2(T, 68),  blk, 0, stream>>>(buf1, e2W[2], e2b[2], buf2, T, 272, 68);
    layer_kernel<1><<<grid2(T, 68),  blk, 0, stream>>>(buf2, e2W[3], e2b[3], buf1, T, 68, 68);
    layer_kernel<0><<<grid2(T, 68),  blk, 0, stream>>>(buf1, e2W[4], e2b[4], (float*)d_out, T, 68, 68);
}